// Round 7
// baseline (366.776 us; speedup 1.0000x reference)
//
#include <hip/hip_runtime.h>

#define NN 50000
#define FF 128
constexpr int CAP = 64;     // bucket capacity (Poisson(10); verified safe)
constexpr int NSL = 8;      // feature slices
constexpr int SLV = 32;     // bf16 values per slice (64 B)

typedef __attribute__((ext_vector_type(4))) short short4v;
typedef __attribute__((ext_vector_type(8))) short short8;
typedef __attribute__((ext_vector_type(4))) float floatx4;

__device__ __forceinline__ unsigned short f2bf(float x) {
    unsigned int u = __float_as_uint(x);
    unsigned int r = (u + 0x7fff + ((u >> 16) & 1)) >> 16;  // RNE
    return (unsigned short)r;
}
__device__ __forceinline__ float bf2f(short x) {
    return __uint_as_float(((unsigned int)(unsigned short)x) << 16);
}

// ---- build: 1/4 of blocks fill edge buckets (atomics), 3/4 convert x0 ----
// to slice-major bf16 layout x0s[s][n][32] (each slice = 3.2MB contiguous).
__global__ __launch_bounds__(256)
void build(const int* __restrict__ dst, const int* __restrict__ src, int E,
           const float* __restrict__ x0,
           const float* __restrict__ w0, const float* __restrict__ w1,
           int* __restrict__ cursor, int* __restrict__ esrc,
           unsigned short* __restrict__ x0s,
           unsigned short* __restrict__ w0b, unsigned short* __restrict__ w1b) {
    int bid = blockIdx.x;
    int t = threadIdx.x;
    if ((bid & 3) == 3) {               // fill role: 512 of 2048 blocks
        int fid = bid >> 2;
        int stride = (gridDim.x >> 2) * 256;
        for (int e = fid * 256 + t; e < E; e += stride) {
            int d = dst[e];
            int pos = atomicAdd(&cursor[d], 1);
            if (pos < CAP) esrc[d * CAP + pos] = src[e];
        }
    } else {                            // convert role: 1536 blocks
        int cid = bid - ((bid + 1) >> 2);
        int i0 = cid * 256 + t;
        int stride = (gridDim.x - (gridDim.x >> 2)) * 256;
        // p indexes 4-value chunks, layout-ordered [s][n][li]
        for (int p = i0; p < NSL * NN * 8; p += stride) {
            int s = p / (NN * 8);
            int rem = p - s * (NN * 8);
            int n = rem >> 3;
            int li = rem & 7;
            int b = s >> 2;
            int f = (s & 3) * SLV + li * 4;
            const float4 in = *(const float4*)&x0[(b * NN + n) * FF + f];
            short4v o = { (short)f2bf(in.x), (short)f2bf(in.y),
                          (short)f2bf(in.z), (short)f2bf(in.w) };
            __builtin_nontemporal_store(o, (short4v*)&x0s[((s * NN) + n) * SLV + li * 4]);
        }
        if (i0 < 128 * 256) w0b[i0] = f2bf(w0[i0]);
        if (i0 < 128 * 128) w1b[i0] = f2bf(w1[i0]);
    }
}

// ---- gather-reduce: slice-per-XCD L2-resident ----
// blockIdx = chunk*8 + slice. Wave: 2 nodes (halves) x 4 edge-slots x 8 lanes
// (short4v = 8B each). 2-deep load unroll. Shuffle-combine xor 8,16.
constexpr int GNPB = 40;

__global__ __launch_bounds__(256)
void gather_reduce(const unsigned short* __restrict__ x0s,
                   const int* __restrict__ cursor,
                   const int* __restrict__ esrc,
                   unsigned short* __restrict__ xcg) {
    int slice = blockIdx.x & 7;
    int chunk = blockIdx.x >> 3;
    int t = threadIdx.x;
    int q = t >> 6;
    int l = t & 63;
    int h  = l >> 5;          // node half
    int lh = l & 31;
    int g  = lh >> 3;         // edge-slot 0..3
    int li = lh & 7;          // value group (4 bf16)
    const unsigned short* xsl = x0s + (size_t)slice * NN * SLV;
    const float NEG_INF = __int_as_float(0xFF800000);

    for (int j = 0; j < GNPB / 8; ++j) {
        int n = chunk * GNPB + j * 8 + q * 2 + h;
        int dg = min(__builtin_nontemporal_load(&cursor[n]), CAP);
        int nbase = n * CAP;
        float s0 = 0.f, s1 = 0.f, s2 = 0.f, s3 = 0.f;
        float m0 = NEG_INF, m1 = NEG_INF, m2 = NEG_INF, m3 = NEG_INF;
        for (int e = 0; e < dg; e += 8) {
            int ee0 = e + g, ee1 = e + 4 + g;
            bool v0ok = ee0 < dg, v1ok = ee1 < dg;
            int idx0 = __builtin_nontemporal_load(&esrc[nbase + (v0ok ? ee0 : 0)]);
            int idx1 = __builtin_nontemporal_load(&esrc[nbase + (v1ok ? ee1 : 0)]);
            short4v r0 = *(const short4v*)&xsl[(unsigned)idx0 * SLV + li * 4];
            short4v r1 = *(const short4v*)&xsl[(unsigned)idx1 * SLV + li * 4];
            if (v0ok) {
                float a = bf2f(r0[0]), b = bf2f(r0[1]), c = bf2f(r0[2]), d = bf2f(r0[3]);
                s0 += a; s1 += b; s2 += c; s3 += d;
                m0 = fmaxf(m0, a); m1 = fmaxf(m1, b); m2 = fmaxf(m2, c); m3 = fmaxf(m3, d);
            }
            if (v1ok) {
                float a = bf2f(r1[0]), b = bf2f(r1[1]), c = bf2f(r1[2]), d = bf2f(r1[3]);
                s0 += a; s1 += b; s2 += c; s3 += d;
                m0 = fmaxf(m0, a); m1 = fmaxf(m1, b); m2 = fmaxf(m2, c); m3 = fmaxf(m3, d);
            }
        }
#pragma unroll
        for (int off = 8; off <= 16; off <<= 1) {
            s0 += __shfl_xor(s0, off); s1 += __shfl_xor(s1, off);
            s2 += __shfl_xor(s2, off); s3 += __shfl_xor(s3, off);
            m0 = fmaxf(m0, __shfl_xor(m0, off)); m1 = fmaxf(m1, __shfl_xor(m1, off));
            m2 = fmaxf(m2, __shfl_xor(m2, off)); m3 = fmaxf(m3, __shfl_xor(m3, off));
        }
        float me0, me1, me2, me3, a0, a1, a2, a3;
        if (dg > 0) {
            float inv = 1.0f / (float)dg;
            me0 = s0 * inv; me1 = s1 * inv; me2 = s2 * inv; me3 = s3 * inv;
            a0 = m0; a1 = m1; a2 = m2; a3 = m3;
        } else {
            short4v rr = *(const short4v*)&xsl[(unsigned)n * SLV + li * 4];
            me0 = a0 = bf2f(rr[0]); me1 = a1 = bf2f(rr[1]);
            me2 = a2 = bf2f(rr[2]); me3 = a3 = bf2f(rr[3]);
        }
        if (lh < 8) {
            short4v mv = { (short)f2bf(me0), (short)f2bf(me1), (short)f2bf(me2), (short)f2bf(me3) };
            short4v av = { (short)f2bf(a0), (short)f2bf(a1), (short)f2bf(a2), (short)f2bf(a3) };
            unsigned base = (unsigned)n * 512 + slice * SLV + li * 4;
            __builtin_nontemporal_store(mv, (short4v*)&xcg[base]);         // mean [0,256)
            __builtin_nontemporal_store(av, (short4v*)&xcg[base + 256]);   // amax [256,512)
        }
    }
}

// ---- MFMA MLP: xcg -> GEMM1 -> relu -> GEMM2 -> out (+fp32 residual) ----
constexpr int NPB = 16;
constexpr int XCP = 256 + 8;
constexpr int HSP = 128 + 8;

__global__ __launch_bounds__(256)
void mlp(const unsigned short* __restrict__ xcg,
         const float* __restrict__ x0,
         const unsigned short* __restrict__ w0b,
         const float* __restrict__ b0,
         const unsigned short* __restrict__ w1b,
         const float* __restrict__ b1,
         float* __restrict__ out) {
    __shared__ unsigned short xc[32 * XCP];
    __shared__ unsigned short hs[32 * HSP];

    int t = threadIdx.x;
    int q = t >> 6;
    int l = t & 63;
    int n0 = blockIdx.x * NPB;

    // stage: xc[row=(j,b)][k] = concat(mean[b], amax[b]) per node
    for (int i = t; i < 1024; i += 256) {
        int row = i >> 5;
        int col = (i & 31) * 8;
        int j = row >> 1, b = row & 1;
        unsigned n = n0 + j;
        unsigned sidx = (col < 128) ? (n * 512 + b * 128 + col)
                                    : (n * 512 + 256 + b * 128 + (col - 128));
        *(short8*)&xc[row * XCP + col] = *(const short8*)&xcg[sidx];
    }
    __syncthreads();

    int m    = l & 15;
    int quad = l >> 4;
    int rowbase = (q >> 1) * 16;
    int colbase = (q & 1) * 64;

    floatx4 acc[4];
#pragma unroll
    for (int ct = 0; ct < 4; ++ct) acc[ct] = (floatx4){0.f, 0.f, 0.f, 0.f};
#pragma unroll
    for (int ks = 0; ks < 8; ++ks) {
        short8 a = *(const short8*)&xc[(rowbase + m) * XCP + ks * 32 + quad * 8];
#pragma unroll
        for (int ct = 0; ct < 4; ++ct) {
            short8 bf = *(const short8*)&w0b[(colbase + ct * 16 + m) * 256 + ks * 32 + quad * 8];
            acc[ct] = __builtin_amdgcn_mfma_f32_16x16x32_bf16(a, bf, acc[ct], 0, 0, 0);
        }
    }
#pragma unroll
    for (int ct = 0; ct < 4; ++ct) {
        int col = colbase + ct * 16 + m;
        float bias = b0[col];
#pragma unroll
        for (int r = 0; r < 4; ++r) {
            int row = rowbase + quad * 4 + r;
            hs[row * HSP + col] = f2bf(fmaxf(acc[ct][r] + bias, 0.0f));
        }
    }
    __syncthreads();

    floatx4 acc2[4];
#pragma unroll
    for (int ct = 0; ct < 4; ++ct) acc2[ct] = (floatx4){0.f, 0.f, 0.f, 0.f};
#pragma unroll
    for (int ks = 0; ks < 4; ++ks) {
        short8 a = *(const short8*)&hs[(rowbase + m) * HSP + ks * 32 + quad * 8];
#pragma unroll
        for (int ct = 0; ct < 4; ++ct) {
            short8 bf = *(const short8*)&w1b[(colbase + ct * 16 + m) * 128 + ks * 32 + quad * 8];
            acc2[ct] = __builtin_amdgcn_mfma_f32_16x16x32_bf16(a, bf, acc2[ct], 0, 0, 0);
        }
    }
#pragma unroll
    for (int ct = 0; ct < 4; ++ct) {
        int col = colbase + ct * 16 + m;
        float bias = b1[col];
#pragma unroll
        for (int r = 0; r < 4; ++r) {
            int row = rowbase + quad * 4 + r;
            int n  = n0 + (row >> 1);
            int b2 = row & 1;
            int oi = (b2 * NN + n) * FF + col;
            float v = x0[oi] + bias + acc2[ct][r];
            __builtin_nontemporal_store(v, &out[oi]);
        }
    }
}

extern "C" void kernel_launch(void* const* d_in, const int* in_sizes, int n_in,
                              void* d_out, int out_size, void* d_ws, size_t ws_size,
                              hipStream_t stream) {
    const float* x0  = (const float*)d_in[0];
    const int*   dst = (const int*)d_in[1];
    const int*   src = (const int*)d_in[2];
    const float* w0  = (const float*)d_in[3];
    const float* b0  = (const float*)d_in[4];
    const float* w1  = (const float*)d_in[5];
    const float* b1  = (const float*)d_in[6];
    float* out = (float*)d_out;
    int E = in_sizes[1];

    int* cursor = (int*)d_ws;                                         // 0.2 MB
    int* esrc   = cursor + NN;                                        // 12.8 MB
    unsigned short* x0s = (unsigned short*)(esrc + (size_t)NN * CAP); // 25.6 MB
    unsigned short* xcg = x0s + (size_t)NSL * NN * SLV;               // 51.2 MB
    unsigned short* w0b = xcg + (size_t)NN * 512;
    unsigned short* w1b = w0b + 128 * 256;

    hipMemsetAsync(cursor, 0, (size_t)NN * sizeof(int), stream);
    build<<<2048, 256, 0, stream>>>(dst, src, E, x0, w0, w1, cursor, esrc, x0s, w0b, w1b);
    gather_reduce<<<(NN / GNPB) * 8, 256, 0, stream>>>(x0s, cursor, esrc, xcg);
    mlp<<<NN / NPB, 256, 0, stream>>>(xcg, x0, w0b, b0, w1b, b1, out);
}

// Round 8
// 307.834 us; speedup vs baseline: 1.1915x; 1.1915x over previous
//
#include <hip/hip_runtime.h>

#define NN 50000
#define FF 128
constexpr int CAP = 64;     // bucket capacity (Poisson(10); never reached)
constexpr int NSL = 8;      // feature slices
constexpr int SLV = 32;     // bf16 values per slice (64 B)

typedef __attribute__((ext_vector_type(4))) short short4v;
typedef __attribute__((ext_vector_type(8))) short short8;
typedef __attribute__((ext_vector_type(4))) float floatx4;

__device__ __forceinline__ unsigned short f2bf(float x) {
    unsigned int u = __float_as_uint(x);
    unsigned int r = (u + 0x7fff + ((u >> 16) & 1)) >> 16;  // RNE
    return (unsigned short)r;
}
__device__ __forceinline__ float bf2f(short x) {
    return __uint_as_float(((unsigned int)(unsigned short)x) << 16);
}

// ---- convert x0 -> slice-major bf16 x0s[s][n][32]; also zero cursor ----
__global__ __launch_bounds__(256)
void convert_x(const float* __restrict__ x0,
               const float* __restrict__ w0, const float* __restrict__ w1,
               int* __restrict__ cursor, unsigned short* __restrict__ x0s,
               unsigned short* __restrict__ w0b, unsigned short* __restrict__ w1b) {
    int i = blockIdx.x * 256 + threadIdx.x;
    if (i < NN) cursor[i] = 0;
    int stride = gridDim.x * 256;
    for (int p = i; p < NSL * NN * 8; p += stride) {
        int s = p / (NN * 8);
        int rem = p - s * (NN * 8);
        int n = rem >> 3;
        int li = rem & 7;
        int b = s >> 2;
        int f = (s & 3) * SLV + li * 4;
        const float4 in = *(const float4*)&x0[(b * NN + n) * FF + f];
        short4v o = { (short)f2bf(in.x), (short)f2bf(in.y),
                      (short)f2bf(in.z), (short)f2bf(in.w) };
        __builtin_nontemporal_store(o, (short4v*)&x0s[((s * NN) + n) * SLV + li * 4]);
    }
    if (i < 128 * 256) w0b[i] = f2bf(w0[i]);
    if (i < 128 * 128) w1b[i] = f2bf(w1[i]);
}

// ---- bucket fill (runs after convert_x, which zeroed cursor) ----
__global__ void fill_edges(const int* __restrict__ dst, const int* __restrict__ src,
                           int E, int* __restrict__ cursor, int* __restrict__ esrc) {
    int e = blockIdx.x * blockDim.x + threadIdx.x;
    if (e < E) {
        int d = dst[e];
        int pos = atomicAdd(&cursor[d], 1);
        if (pos < CAP) esrc[d * CAP + pos] = src[e];
    }
}

// ---- gather-reduce: slot-per-node, slice-per-XCD ----
// blockIdx = chunk*8 + slice. Wave = 8 slots (g = node) x 8 lanes (li = 4-value
// group): a slot's 8 lanes hold the whole 32-value slice -> NO cross-lane
// reduction. Edge loop over dgmax (wave max), 4 edges/iter, all loads
// unconditional with clamped index (self-row for padding -> L1 hit).
constexpr int GNPB = 32;  // nodes per block (4 waves x 8 slots)

__global__ __launch_bounds__(256)
void gather_reduce(const unsigned short* __restrict__ x0s,
                   const int* __restrict__ cursor,
                   const int* __restrict__ esrc,
                   unsigned short* __restrict__ xcg) {
    int slice = blockIdx.x & 7;
    int chunk = blockIdx.x >> 3;
    int t = threadIdx.x;
    int wv = t >> 6, l = t & 63;
    int g = l >> 3, li = l & 7;
    const unsigned short* xsl = x0s + (size_t)slice * NN * SLV;

    int n = chunk * GNPB + wv * 8 + g;
    bool nok = n < NN;
    int ns = nok ? n : 0;
    int dg = nok ? min(cursor[ns], CAP) : 0;
    int dgmax = dg;
    dgmax = max(dgmax, __shfl_xor(dgmax, 8));
    dgmax = max(dgmax, __shfl_xor(dgmax, 16));
    dgmax = max(dgmax, __shfl_xor(dgmax, 32));
    int dgm1 = max(dg - 1, 0);
    int eb = ns * CAP;
    const float NEG_INF = __int_as_float(0xFF800000);

    float s0 = 0.f, s1 = 0.f, s2 = 0.f, s3 = 0.f;
    float m0 = NEG_INF, m1 = NEG_INF, m2 = NEG_INF, m3 = NEG_INF;

#define ACCR(r) { \
        float a = bf2f((r)[0]), b = bf2f((r)[1]), c = bf2f((r)[2]), d = bf2f((r)[3]); \
        s0 += a; s1 += b; s2 += c; s3 += d; \
        m0 = fmaxf(m0, a); m1 = fmaxf(m1, b); m2 = fmaxf(m2, c); m3 = fmaxf(m3, d); }

    for (int e = 0; e < dgmax; e += 4) {
        int o0 = min(e,     dgm1), o1 = min(e + 1, dgm1);
        int o2 = min(e + 2, dgm1), o3 = min(e + 3, dgm1);
        int i0 = esrc[eb + o0], i1 = esrc[eb + o1];
        int i2 = esrc[eb + o2], i3 = esrc[eb + o3];
        i0 = (e     < dg) ? i0 : ns;
        i1 = (e + 1 < dg) ? i1 : ns;
        i2 = (e + 2 < dg) ? i2 : ns;
        i3 = (e + 3 < dg) ? i3 : ns;
        short4v r0 = *(const short4v*)&xsl[(unsigned)i0 * SLV + li * 4];
        short4v r1 = *(const short4v*)&xsl[(unsigned)i1 * SLV + li * 4];
        short4v r2 = *(const short4v*)&xsl[(unsigned)i2 * SLV + li * 4];
        short4v r3 = *(const short4v*)&xsl[(unsigned)i3 * SLV + li * 4];
        if (e     < dg) ACCR(r0);
        if (e + 1 < dg) ACCR(r1);
        if (e + 2 < dg) ACCR(r2);
        if (e + 3 < dg) ACCR(r3);
    }
#undef ACCR

    short4v rs = *(const short4v*)&xsl[(unsigned)ns * SLV + li * 4];  // self row
    float inv = 1.0f / (float)max(dg, 1);
    float me0, me1, me2, me3, a0, a1, a2, a3;
    if (dg > 0) {
        me0 = s0 * inv; me1 = s1 * inv; me2 = s2 * inv; me3 = s3 * inv;
        a0 = m0; a1 = m1; a2 = m2; a3 = m3;
    } else {
        me0 = a0 = bf2f(rs[0]); me1 = a1 = bf2f(rs[1]);
        me2 = a2 = bf2f(rs[2]); me3 = a3 = bf2f(rs[3]);
    }
    if (nok) {
        short4v mv = { (short)f2bf(me0), (short)f2bf(me1), (short)f2bf(me2), (short)f2bf(me3) };
        short4v av = { (short)f2bf(a0), (short)f2bf(a1), (short)f2bf(a2), (short)f2bf(a3) };
        unsigned base = (unsigned)n * 512 + slice * SLV + li * 4;
        __builtin_nontemporal_store(mv, (short4v*)&xcg[base]);         // mean [0,256)
        __builtin_nontemporal_store(av, (short4v*)&xcg[base + 256]);   // amax [256,512)
    }
}

// ---- MFMA MLP: xcg -> GEMM1 -> relu -> GEMM2 -> out (+fp32 residual) ----
constexpr int NPB = 16;
constexpr int XCP = 256 + 8;
constexpr int HSP = 128 + 8;

__global__ __launch_bounds__(256)
void mlp(const unsigned short* __restrict__ xcg,
         const float* __restrict__ x0,
         const unsigned short* __restrict__ w0b,
         const float* __restrict__ b0,
         const unsigned short* __restrict__ w1b,
         const float* __restrict__ b1,
         float* __restrict__ out) {
    __shared__ unsigned short xc[32 * XCP];
    __shared__ unsigned short hs[32 * HSP];

    int t = threadIdx.x;
    int q = t >> 6;
    int l = t & 63;
    int n0 = blockIdx.x * NPB;

    for (int i = t; i < 1024; i += 256) {
        int row = i >> 5;
        int col = (i & 31) * 8;
        int j = row >> 1, b = row & 1;
        unsigned n = n0 + j;
        unsigned sidx = (col < 128) ? (n * 512 + b * 128 + col)
                                    : (n * 512 + 256 + b * 128 + (col - 128));
        *(short8*)&xc[row * XCP + col] = *(const short8*)&xcg[sidx];
    }
    __syncthreads();

    int m    = l & 15;
    int quad = l >> 4;
    int rowbase = (q >> 1) * 16;
    int colbase = (q & 1) * 64;

    floatx4 acc[4];
#pragma unroll
    for (int ct = 0; ct < 4; ++ct) acc[ct] = (floatx4){0.f, 0.f, 0.f, 0.f};
#pragma unroll
    for (int ks = 0; ks < 8; ++ks) {
        short8 a = *(const short8*)&xc[(rowbase + m) * XCP + ks * 32 + quad * 8];
#pragma unroll
        for (int ct = 0; ct < 4; ++ct) {
            short8 bf = *(const short8*)&w0b[(colbase + ct * 16 + m) * 256 + ks * 32 + quad * 8];
            acc[ct] = __builtin_amdgcn_mfma_f32_16x16x32_bf16(a, bf, acc[ct], 0, 0, 0);
        }
    }
#pragma unroll
    for (int ct = 0; ct < 4; ++ct) {
        int col = colbase + ct * 16 + m;
        float bias = b0[col];
#pragma unroll
        for (int r = 0; r < 4; ++r) {
            int row = rowbase + quad * 4 + r;
            hs[row * HSP + col] = f2bf(fmaxf(acc[ct][r] + bias, 0.0f));
        }
    }
    __syncthreads();

    floatx4 acc2[4];
#pragma unroll
    for (int ct = 0; ct < 4; ++ct) acc2[ct] = (floatx4){0.f, 0.f, 0.f, 0.f};
#pragma unroll
    for (int ks = 0; ks < 4; ++ks) {
        short8 a = *(const short8*)&hs[(rowbase + m) * HSP + ks * 32 + quad * 8];
#pragma unroll
        for (int ct = 0; ct < 4; ++ct) {
            short8 bf = *(const short8*)&w1b[(colbase + ct * 16 + m) * 128 + ks * 32 + quad * 8];
            acc2[ct] = __builtin_amdgcn_mfma_f32_16x16x32_bf16(a, bf, acc2[ct], 0, 0, 0);
        }
    }
#pragma unroll
    for (int ct = 0; ct < 4; ++ct) {
        int col = colbase + ct * 16 + m;
        float bias = b1[col];
#pragma unroll
        for (int r = 0; r < 4; ++r) {
            int row = rowbase + quad * 4 + r;
            int n  = n0 + (row >> 1);
            int b2 = row & 1;
            int oi = (b2 * NN + n) * FF + col;
            float v = x0[oi] + bias + acc2[ct][r];
            __builtin_nontemporal_store(v, &out[oi]);
        }
    }
}

extern "C" void kernel_launch(void* const* d_in, const int* in_sizes, int n_in,
                              void* d_out, int out_size, void* d_ws, size_t ws_size,
                              hipStream_t stream) {
    const float* x0  = (const float*)d_in[0];
    const int*   dst = (const int*)d_in[1];
    const int*   src = (const int*)d_in[2];
    const float* w0  = (const float*)d_in[3];
    const float* b0  = (const float*)d_in[4];
    const float* w1  = (const float*)d_in[5];
    const float* b1  = (const float*)d_in[6];
    float* out = (float*)d_out;
    int E = in_sizes[1];

    int* cursor = (int*)d_ws;                                         // 0.2 MB
    int* esrc   = cursor + NN;                                        // 12.8 MB
    unsigned short* x0s = (unsigned short*)(esrc + (size_t)NN * CAP); // 25.6 MB
    unsigned short* xcg = x0s + (size_t)NSL * NN * SLV;               // 51.2 MB
    unsigned short* w0b = xcg + (size_t)NN * 512;
    unsigned short* w1b = w0b + 128 * 256;

    int gchunks = (NN + GNPB - 1) / GNPB;   // 1563

    convert_x<<<2048, 256, 0, stream>>>(x0, w0, w1, cursor, x0s, w0b, w1b);
    fill_edges<<<(E + 255) / 256, 256, 0, stream>>>(dst, src, E, cursor, esrc);
    gather_reduce<<<gchunks * 8, 256, 0, stream>>>(x0s, cursor, esrc, xcg);
    mlp<<<NN / NPB, 256, 0, stream>>>(xcg, x0, w0b, b0, w1b, b1, out);
}

// Round 10
// 300.357 us; speedup vs baseline: 1.2211x; 1.0249x over previous
//
#include <hip/hip_runtime.h>

#define NN 50000
#define FF 128
constexpr int CAP = 64;     // bucket capacity (Poisson(10); never reached)
constexpr int NSL = 8;      // feature slices
constexpr int SLV = 32;     // bf16 values per slice (64 B)

typedef __attribute__((ext_vector_type(4))) short short4v;
typedef __attribute__((ext_vector_type(8))) short short8;
typedef __attribute__((ext_vector_type(4))) float floatx4;

__device__ __forceinline__ unsigned short f2bf(float x) {
    unsigned int u = __float_as_uint(x);
    unsigned int r = (u + 0x7fff + ((u >> 16) & 1)) >> 16;  // RNE
    return (unsigned short)r;
}
__device__ __forceinline__ float bf2f(short x) {
    return __uint_as_float(((unsigned int)(unsigned short)x) << 16);
}

// ---- build: role-split. Half the blocks convert x0 -> x0s (slice-major
// bf16) + weights; other half fill edge buckets (atomics). cursor zeroed by
// the preceding memset.
__global__ __launch_bounds__(256)
void build(const int* __restrict__ dst, const int* __restrict__ src, int E,
           const float* __restrict__ x0,
           const float* __restrict__ w0, const float* __restrict__ w1,
           int* __restrict__ cursor, int* __restrict__ esrc,
           unsigned short* __restrict__ x0s,
           unsigned short* __restrict__ w0b, unsigned short* __restrict__ w1b) {
    int bid = blockIdx.x;
    int t = threadIdx.x;
    int half = gridDim.x >> 1;
    if (bid >= half) {                  // fill role
        int e = (bid - half) * 256 + t;
        if (e < E) {
            int d = dst[e];
            int pos = atomicAdd(&cursor[d], 1);
            if (pos < CAP) esrc[d * CAP + pos] = src[e];
        }
        return;
    }
    // convert role
    int i0 = bid * 256 + t;
    int stride = half * 256;
    for (int p = i0; p < NSL * NN * 8; p += stride) {
        int s = p / (NN * 8);
        int rem = p - s * (NN * 8);
        int n = rem >> 3;
        int li = rem & 7;
        int b = s >> 2;
        int f = (s & 3) * SLV + li * 4;
        const float4 in = *(const float4*)&x0[(b * NN + n) * FF + f];
        short4v o = { (short)f2bf(in.x), (short)f2bf(in.y),
                      (short)f2bf(in.z), (short)f2bf(in.w) };
        __builtin_nontemporal_store(o, (short4v*)&x0s[((s * NN) + n) * SLV + li * 4]);
    }
    if (i0 < 128 * 256) w0b[i0] = f2bf(w0[i0]);
    if (i0 < 128 * 128) w1b[i0] = f2bf(w1[i0]);
}

// ---- gather-reduce: slot-per-node, slice-per-XCD, slice-major output ----
constexpr int GNPB = 32;  // nodes per block (4 waves x 8 slots)

__global__ __launch_bounds__(256)
void gather_reduce(const unsigned short* __restrict__ x0s,
                   const int* __restrict__ cursor,
                   const int* __restrict__ esrc,
                   unsigned short* __restrict__ xcgm,
                   unsigned short* __restrict__ xcga) {
    int slice = blockIdx.x & 7;
    int chunk = blockIdx.x >> 3;
    int t = threadIdx.x;
    int wv = t >> 6, l = t & 63;
    int g = l >> 3, li = l & 7;
    const unsigned short* xsl = x0s + (size_t)slice * NN * SLV;

    int n = chunk * GNPB + wv * 8 + g;
    bool nok = n < NN;
    int ns = nok ? n : 0;
    int dg = nok ? min(cursor[ns], CAP) : 0;
    int dgmax = dg;
    dgmax = max(dgmax, __shfl_xor(dgmax, 8));
    dgmax = max(dgmax, __shfl_xor(dgmax, 16));
    dgmax = max(dgmax, __shfl_xor(dgmax, 32));
    int dgm1 = max(dg - 1, 0);
    int eb = ns * CAP;
    const float NEG_INF = __int_as_float(0xFF800000);

    float s0 = 0.f, s1 = 0.f, s2 = 0.f, s3 = 0.f;
    float m0 = NEG_INF, m1 = NEG_INF, m2 = NEG_INF, m3 = NEG_INF;

#define ACCR(r) { \
        float a = bf2f((r)[0]), b = bf2f((r)[1]), c = bf2f((r)[2]), d = bf2f((r)[3]); \
        s0 += a; s1 += b; s2 += c; s3 += d; \
        m0 = fmaxf(m0, a); m1 = fmaxf(m1, b); m2 = fmaxf(m2, c); m3 = fmaxf(m3, d); }

    for (int e = 0; e < dgmax; e += 4) {
        int o0 = min(e,     dgm1), o1 = min(e + 1, dgm1);
        int o2 = min(e + 2, dgm1), o3 = min(e + 3, dgm1);
        int i0 = esrc[eb + o0], i1 = esrc[eb + o1];
        int i2 = esrc[eb + o2], i3 = esrc[eb + o3];
        i0 = (e     < dg) ? i0 : ns;
        i1 = (e + 1 < dg) ? i1 : ns;
        i2 = (e + 2 < dg) ? i2 : ns;
        i3 = (e + 3 < dg) ? i3 : ns;
        short4v r0 = *(const short4v*)&xsl[(unsigned)i0 * SLV + li * 4];
        short4v r1 = *(const short4v*)&xsl[(unsigned)i1 * SLV + li * 4];
        short4v r2 = *(const short4v*)&xsl[(unsigned)i2 * SLV + li * 4];
        short4v r3 = *(const short4v*)&xsl[(unsigned)i3 * SLV + li * 4];
        if (e     < dg) ACCR(r0);
        if (e + 1 < dg) ACCR(r1);
        if (e + 2 < dg) ACCR(r2);
        if (e + 3 < dg) ACCR(r3);
    }
#undef ACCR

    short4v rs = *(const short4v*)&xsl[(unsigned)ns * SLV + li * 4];  // self row
    float me0, me1, me2, me3, a0, a1, a2, a3;
    if (dg > 0) {
        float inv = 1.0f / (float)dg;
        me0 = s0 * inv; me1 = s1 * inv; me2 = s2 * inv; me3 = s3 * inv;
        a0 = m0; a1 = m1; a2 = m2; a3 = m3;
    } else {
        me0 = a0 = bf2f(rs[0]); me1 = a1 = bf2f(rs[1]);
        me2 = a2 = bf2f(rs[2]); me3 = a3 = bf2f(rs[3]);
    }
    if (nok) {
        short4v mv = { (short)f2bf(me0), (short)f2bf(me1), (short)f2bf(me2), (short)f2bf(me3) };
        short4v av = { (short)f2bf(a0), (short)f2bf(a1), (short)f2bf(a2), (short)f2bf(a3) };
        // slice-major: per wave 8 consecutive nodes x 64B = 512B contiguous
        unsigned base = ((unsigned)slice * NN + n) * SLV + li * 4;
        __builtin_nontemporal_store(mv, (short4v*)&xcgm[base]);
        __builtin_nontemporal_store(av, (short4v*)&xcga[base]);
    }
}

// ---- MFMA MLP ----
constexpr int NPB = 16;
constexpr int XCP = 256 + 8;   // ushort pitch; also reused as fp32[32][132]
constexpr int HSP = 128 + 8;

__global__ __launch_bounds__(256)
void mlp(const unsigned short* __restrict__ xcgm,
         const unsigned short* __restrict__ xcga,
         const float* __restrict__ x0,
         const unsigned short* __restrict__ w0b,
         const float* __restrict__ b0,
         const unsigned short* __restrict__ w1b,
         const float* __restrict__ b1,
         float* __restrict__ out) {
    __shared__ unsigned short xc[32 * XCP];   // 16.9 KB (exactly 32*132 floats)
    __shared__ unsigned short hs[32 * HSP];

    int t = threadIdx.x;
    int q = t >> 6;
    int l = t & 63;
    int n0 = blockIdx.x * NPB;

    // stage: 2048 chunks of 8B over [kind(2)][slice(8)][node(16)][li(8)]
    for (int i = t; i < 2048; i += 256) {
        int kind = i >> 10;
        int r1 = i & 1023;
        int s = r1 >> 7;
        int r2 = r1 & 127;
        int j = r2 >> 3;
        int li = r2 & 7;
        const unsigned short* srcp = kind ? xcga : xcgm;
        short4v v = *(const short4v*)&srcp[((size_t)s * NN + n0 + j) * SLV + li * 4];
        int b = s >> 2;
        int col = (s & 3) * SLV + li * 4 + kind * 128;
        *(short4v*)&xc[(j * 2 + b) * XCP + col] = v;
    }
    __syncthreads();

    int m    = l & 15;
    int quad = l >> 4;
    int rowbase = (q >> 1) * 16;
    int colbase = (q & 1) * 64;

    floatx4 acc[4];
#pragma unroll
    for (int ct = 0; ct < 4; ++ct) acc[ct] = (floatx4){0.f, 0.f, 0.f, 0.f};
#pragma unroll
    for (int ks = 0; ks < 8; ++ks) {
        short8 a = *(const short8*)&xc[(rowbase + m) * XCP + ks * 32 + quad * 8];
#pragma unroll
        for (int ct = 0; ct < 4; ++ct) {
            short8 bf = *(const short8*)&w0b[(colbase + ct * 16 + m) * 256 + ks * 32 + quad * 8];
            acc[ct] = __builtin_amdgcn_mfma_f32_16x16x32_bf16(a, bf, acc[ct], 0, 0, 0);
        }
    }
#pragma unroll
    for (int ct = 0; ct < 4; ++ct) {
        int col = colbase + ct * 16 + m;
        float bias = b0[col];
#pragma unroll
        for (int r = 0; r < 4; ++r) {
            int row = rowbase + quad * 4 + r;
            hs[row * HSP + col] = f2bf(fmaxf(acc[ct][r] + bias, 0.0f));
        }
    }
    __syncthreads();   // also: all xc reads complete beyond this point

    floatx4 acc2[4];
#pragma unroll
    for (int ct = 0; ct < 4; ++ct) acc2[ct] = (floatx4){0.f, 0.f, 0.f, 0.f};
#pragma unroll
    for (int ks = 0; ks < 4; ++ks) {
        short8 a = *(const short8*)&hs[(rowbase + m) * HSP + ks * 32 + quad * 8];
#pragma unroll
        for (int ct = 0; ct < 4; ++ct) {
            short8 bf = *(const short8*)&w1b[(colbase + ct * 16 + m) * 128 + ks * 32 + quad * 8];
            acc2[ct] = __builtin_amdgcn_mfma_f32_16x16x32_bf16(a, bf, acc2[ct], 0, 0, 0);
        }
    }
    // epilogue: acc2+bias -> LDS fp32 (reuse xc), then coalesced float4 out
    float* xcf = (float*)xc;   // [32][132]
#pragma unroll
    for (int ct = 0; ct < 4; ++ct) {
        int col = colbase + ct * 16 + m;
        float bias = b1[col];
#pragma unroll
        for (int r = 0; r < 4; ++r) {
            int row = rowbase + quad * 4 + r;
            xcf[row * 132 + col] = acc2[ct][r] + bias;
        }
    }
    __syncthreads();
    for (int c = t; c < 1024; c += 256) {
        int row = c >> 5;
        int cw  = (c & 31) * 4;
        int j  = row >> 1;
        int b2 = row & 1;
        int n  = n0 + j;
        int oi = (b2 * NN + n) * FF + cw;
        floatx4 hv = *(const floatx4*)&xcf[row * 132 + cw];
        floatx4 xv = *(const floatx4*)&x0[oi];
        floatx4 ov = hv + xv;
        __builtin_nontemporal_store(ov, (floatx4*)&out[oi]);
    }
}

extern "C" void kernel_launch(void* const* d_in, const int* in_sizes, int n_in,
                              void* d_out, int out_size, void* d_ws, size_t ws_size,
                              hipStream_t stream) {
    const float* x0  = (const float*)d_in[0];
    const int*   dst = (const int*)d_in[1];
    const int*   src = (const int*)d_in[2];
    const float* w0  = (const float*)d_in[3];
    const float* b0  = (const float*)d_in[4];
    const float* w1  = (const float*)d_in[5];
    const float* b1  = (const float*)d_in[6];
    float* out = (float*)d_out;
    int E = in_sizes[1];

    int* cursor = (int*)d_ws;                                          // 0.2 MB
    int* esrc   = cursor + NN;                                         // 12.8 MB
    unsigned short* x0s  = (unsigned short*)(esrc + (size_t)NN * CAP); // 25.6 MB
    unsigned short* xcgm = x0s + (size_t)NSL * NN * SLV;               // 25.6 MB
    unsigned short* xcga = xcgm + (size_t)NSL * NN * SLV;              // 25.6 MB
    unsigned short* w0b  = xcga + (size_t)NSL * NN * SLV;
    unsigned short* w1b  = w0b + 128 * 256;

    int fillb = (E + 255) / 256;            // 1954
    int convb = 2048;
    int gchunks = (NN + GNPB - 1) / GNPB;   // 1563

    (void)hipMemsetAsync(cursor, 0, (size_t)NN * sizeof(int), stream);
    build<<<convb + fillb, 256, 0, stream>>>(dst, src, E, x0, w0, w1,
                                             cursor, esrc, x0s, w0b, w1b);
    gather_reduce<<<gchunks * 8, 256, 0, stream>>>(x0s, cursor, esrc, xcgm, xcga);
    mlp<<<NN / NPB, 256, 0, stream>>>(xcgm, xcga, x0, w0b, b0, w1b, b1, out);
}